// Round 10
// baseline (75.950 us; speedup 1.0000x reference)
//
#include <hip/hip_runtime.h>
#include <stdint.h>
#include <stddef.h>

// MultiTaskTrunkNetwork: 3x (Linear+Tanh) [89->64->64->64] + per-task head [64->8]
// Round 10: MoE-style split. Trunk kernel (r8 verbatim trunk) writes h to ws;
// rows task-sorted via histogram+prefix+scatter; head kernel processes sorted
// rows so each wave's head-weight block is cache-resident (262MB -> ~50MB).
// Fallback to the r8 fused kernel if ws_size is too small.

typedef _Float16 half8 __attribute__((ext_vector_type(8)));
typedef _Float16 half4 __attribute__((ext_vector_type(4)));
typedef _Float16 half2v __attribute__((ext_vector_type(2)));
typedef float    f32x4 __attribute__((ext_vector_type(4)));

constexpr int BN = 262144, INF = 89, HID = 64, OUTF = 8, NTASK = 50;
constexpr int NTHR = 128;     // 2 waves (trunk)
constexpr int ROWS = 64;      // batch rows per trunk block (32 per wave)
constexpr int XP   = 104;     // LDS row pitch in f16 (208 B)
constexpr int XTILE_V4 = ROWS * INF / 4;   // 1424 float4 = 11*128 + 16

// d_ws layout (bytes)
constexpr int    W0F_OFF  = 0;         // [3kk][4ft][64lane][8] f16 (k>=89 zero)
constexpr int    W1F_OFF  = 12288;     // [2kk][4ft][64lane][8] f16
constexpr int    W2F_OFF  = 20480;     // [2kk][4ft][64lane][8] f16
constexpr int    HWT_OFF  = 28672;     // [50][8][64] f16 transposed head weights
constexpr size_t H_OFF    = 79872;     // [B][64] f16 hidden
constexpr size_t IDX_OFF  = H_OFF + (size_t)BN * HID * 2;        // [B] i32 sorted rows
constexpr size_t HIST_OFF = IDX_OFF + (size_t)BN * 4;            // [64] i32
constexpr size_t BASE_OFF = HIST_OFF + 256;                      // [64] i32
constexpr size_t WS_NEED  = BASE_OFF + 256;

__device__ __forceinline__ float fast_tanh(float v) {
    float e = __expf(2.0f * v);
    return 1.0f - 2.0f * __builtin_amdgcn_rcpf(e + 1.0f);
}

__device__ __forceinline__ float dot2acc(half2v a, half2v b, float c) {
#if __has_builtin(__builtin_amdgcn_fdot2)
    return __builtin_amdgcn_fdot2(a, b, c, false);
#else
    return fmaf((float)a[0], (float)b[0], fmaf((float)a[1], (float)b[1], c));
#endif
}

__global__ void prep_kernel(const float* __restrict__ W0, const float* __restrict__ W1,
                            const float* __restrict__ W2, const float* __restrict__ hW,
                            _Float16* __restrict__ ws) {
    const int tid = blockIdx.x * blockDim.x + threadIdx.x;
    const int stride = gridDim.x * blockDim.x;
    _Float16* w0f = ws + W0F_OFF / 2;
    _Float16* w1f = ws + W1F_OFF / 2;
    _Float16* w2f = ws + W2F_OFF / 2;
    _Float16* hwt = ws + HWT_OFF / 2;
    for (int i = tid; i < 3 * 4 * 64 * 8; i += stride) {
        int j = i & 7, l = (i >> 3) & 63, fk = i >> 9;   // fk = kk*4+ft
        int kk = fk >> 2, ft = fk & 3;
        int n = ft * 16 + (l & 15);
        int k = kk * 32 + (l >> 4) * 8 + j;
        w0f[i] = (_Float16)(k < INF ? W0[k * HID + n] : 0.0f);
    }
    for (int i = tid; i < 2 * 4 * 64 * 8; i += stride) {
        int j = i & 7, l = (i >> 3) & 63, fk = i >> 9;
        int kk = fk >> 2, ft = fk & 3;
        int n = ft * 16 + (l & 15);
        int k = kk * 32 + (l >> 4) * 8 + j;
        w1f[i] = (_Float16)W1[k * HID + n];
        w2f[i] = (_Float16)W2[k * HID + n];
    }
    for (int i = tid; i < NTASK * OUTF * HID; i += stride) {   // hwT[t][o][k]
        int t = i / (OUTF * HID), rem = i % (OUTF * HID);
        int o = rem / HID, k = rem % HID;
        hwt[i] = (_Float16)hW[(size_t)t * (HID * OUTF) + k * OUTF + o];
    }
}

// ---------------- sort chain ----------------
__global__ void sort_init(int* __restrict__ hist, int* __restrict__ base) {
    int t = threadIdx.x;
    if (t < 64) { hist[t] = 0; base[t] = 0; }
}

__global__ __launch_bounds__(256) void sort_hist(const int* __restrict__ task,
                                                 int* __restrict__ hist) {
    __shared__ int lh[NTASK];
    const int t = threadIdx.x;
    if (t < NTASK) lh[t] = 0;
    __syncthreads();
    const int base = blockIdx.x * 1024;
    #pragma unroll
    for (int k = 0; k < 4; ++k) atomicAdd(&lh[task[base + t + k * 256]], 1);
    __syncthreads();
    if (t < NTASK) atomicAdd(&hist[t], lh[t]);
}

__global__ void sort_prefix(const int* __restrict__ hist, int* __restrict__ base) {
    if (threadIdx.x == 0) {
        int run = 0;
        for (int i = 0; i < NTASK; ++i) { base[i] = run; run += hist[i]; }
    }
}

__global__ __launch_bounds__(256) void sort_scatter(const int* __restrict__ task,
                                                    int* __restrict__ base,
                                                    int* __restrict__ idx) {
    __shared__ int lcnt[NTASK];
    __shared__ int lbase[NTASK];
    const int t = threadIdx.x;
    if (t < NTASK) lcnt[t] = 0;
    __syncthreads();
    const int rbase = blockIdx.x * 1024;
    int tk[4], rank[4];
    #pragma unroll
    for (int k = 0; k < 4; ++k) {
        tk[k] = task[rbase + t + k * 256];
        rank[k] = atomicAdd(&lcnt[tk[k]], 1);
    }
    __syncthreads();
    if (t < NTASK) lbase[t] = atomicAdd(&base[t], lcnt[t]);
    __syncthreads();
    #pragma unroll
    for (int k = 0; k < 4; ++k)
        idx[lbase[tk[k]] + rank[k]] = rbase + t + k * 256;
}

// ---------------- trunk kernel (r8 trunk, head replaced by h write) ----------------
__global__ __launch_bounds__(NTHR, 8) void trunk_kernel(
    const float* __restrict__ x,
    const float* __restrict__ b0, const float* __restrict__ b1,
    const float* __restrict__ b2,
    const _Float16* __restrict__ ws,
    _Float16* __restrict__ hbuf)     // [B][64] f16
{
    __shared__ __align__(16) _Float16 xh[ROWS * XP];

    const int t = threadIdx.x;
    const int w = t >> 6;
    const int l = t & 63;
    const int c = l & 15;
    const int g = l >> 4;
    const int blockRow = blockIdx.x * ROWS;
    const int waveRow  = w * 32;

    const _Float16* w0f = ws + W0F_OFF / 2;
    const _Float16* w1f = ws + W1F_OFF / 2;
    const _Float16* w2f = ws + W2F_OFF / 2;

    // ---- stage x tile: coalesced float4 -> f16 LDS [row][k], pitch 104
    {
        const float4* xb = reinterpret_cast<const float4*>(x + (size_t)blockRow * INF);
        #pragma unroll
        for (int i = 0; i < 12; ++i) {
            if (i < 11 || t < XTILE_V4 - 11 * NTHR) {        // 1424 = 11*128 + 16
                float4 v = xb[t + i * NTHR];
                int e = 4 * (t + i * NTHR);
                #pragma unroll
                for (int q = 0; q < 4; ++q) {
                    int ee = e + q;
                    int rr = ee / INF, k = ee - rr * INF;
                    xh[rr * XP + k] = (_Float16)((q == 0) ? v.x : (q == 1) ? v.y
                                                 : (q == 2) ? v.z : v.w);
                }
            }
        }
        if (t < ROWS) {
            #pragma unroll
            for (int k = INF; k < 96; ++k) xh[t * XP + k] = (_Float16)0;
        }
    }
    __syncthreads();

    f32x4 acc[4][2];

    // layer 0
    #pragma unroll
    for (int ft = 0; ft < 4; ++ft) {
        f32x4 bv = *(const f32x4*)(b0 + ft * 16 + g * 4);
        acc[ft][0] = bv; acc[ft][1] = bv;
    }
    #pragma unroll
    for (int kk = 0; kk < 3; ++kk) {
        half8 bf[2];
        #pragma unroll
        for (int bt = 0; bt < 2; ++bt)
            bf[bt] = *(const half8*)&xh[(waveRow + bt * 16 + c) * XP + kk * 32 + g * 8];
        #pragma unroll
        for (int ft = 0; ft < 4; ++ft) {
            half8 af = *(const half8*)(w0f + ((kk * 4 + ft) * 64 + l) * 8);
            acc[ft][0] = __builtin_amdgcn_mfma_f32_16x16x32_f16(af, bf[0], acc[ft][0], 0, 0, 0);
            acc[ft][1] = __builtin_amdgcn_mfma_f32_16x16x32_f16(af, bf[1], acc[ft][1], 0, 0, 0);
        }
    }
    #pragma unroll
    for (int ft = 0; ft < 4; ++ft)
        #pragma unroll
        for (int bt = 0; bt < 2; ++bt) {
            half4 hv;
            #pragma unroll
            for (int r = 0; r < 4; ++r) hv[r] = (_Float16)fast_tanh(acc[ft][bt][r]);
            *(half4*)&xh[(waveRow + bt * 16 + c) * XP + ft * 16 + g * 4] = hv;
        }

    // layers 1,2
    #pragma unroll
    for (int layer = 0; layer < 2; ++layer) {
        const _Float16* WF  = layer ? w2f : w1f;
        const float*    bia = layer ? b2  : b1;
        #pragma unroll
        for (int ft = 0; ft < 4; ++ft) {
            f32x4 bv = *(const f32x4*)(bia + ft * 16 + g * 4);
            acc[ft][0] = bv; acc[ft][1] = bv;
        }
        #pragma unroll
        for (int kk = 0; kk < 2; ++kk) {
            half8 bf[2];
            #pragma unroll
            for (int bt = 0; bt < 2; ++bt)
                bf[bt] = *(const half8*)&xh[(waveRow + bt * 16 + c) * XP + kk * 32 + g * 8];
            #pragma unroll
            for (int ft = 0; ft < 4; ++ft) {
                half8 af = *(const half8*)(WF + ((kk * 4 + ft) * 64 + l) * 8);
                acc[ft][0] = __builtin_amdgcn_mfma_f32_16x16x32_f16(af, bf[0], acc[ft][0], 0, 0, 0);
                acc[ft][1] = __builtin_amdgcn_mfma_f32_16x16x32_f16(af, bf[1], acc[ft][1], 0, 0, 0);
            }
        }
        #pragma unroll
        for (int ft = 0; ft < 4; ++ft)
            #pragma unroll
            for (int bt = 0; bt < 2; ++bt) {
                half4 hv;
                #pragma unroll
                for (int r = 0; r < 4; ++r) hv[r] = (_Float16)fast_tanh(acc[ft][bt][r]);
                *(half4*)&xh[(waveRow + bt * 16 + c) * XP + ft * 16 + g * 4] = hv;
            }
    }

    // write h coalesced: per it one ds_read_b128 + one 16B store (1KB/instr/wave)
    const int jr = l >> 3, jo = l & 7;
    #pragma unroll
    for (int it = 0; it < 4; ++it) {
        const int r = it * 8 + jr;
        const size_t grow = (size_t)blockRow + waveRow + r;
        half8 hv = *(const half8*)&xh[(waveRow + r) * XP + jo * 8];
        *(half8*)(hbuf + grow * HID + jo * 8) = hv;
    }
}

// ---------------- head kernel: task-sorted rows ----------------
__global__ __launch_bounds__(256, 8) void head_kernel(
    const int* __restrict__ idx,     // sorted row indices
    const int* __restrict__ task,
    const _Float16* __restrict__ ws,
    const float* __restrict__ hB,
    float* __restrict__ out)
{
    const int t = threadIdx.x;
    const int w = t >> 6;
    const int l = t & 63;
    const int jr = l >> 3, jo = l & 7;
    const int sbase = (blockIdx.x * 4 + w) * 32;
    const _Float16* hwt  = ws + HWT_OFF / 2;
    const _Float16* hbuf = ws + H_OFF / 2;

    int rdx[4];
    #pragma unroll
    for (int it = 0; it < 4; ++it) rdx[it] = idx[sbase + it * 8 + jr];
    int tks[4];
    #pragma unroll
    for (int it = 0; it < 4; ++it) tks[it] = task[rdx[it]];

    #pragma unroll
    for (int it = 0; it < 4; ++it) {
        const int tk = tks[it];
        const _Float16* wp = hwt + (size_t)tk * (OUTF * HID) + jo * 8;   // chunk jo
        const half8 hv = *(const half8*)(hbuf + (size_t)rdx[it] * HID + jo * 8);
        const float hb = hB[tk * OUTF + jo];

        float p[8];
        #pragma unroll
        for (int o = 0; o < 8; ++o) {
            half8 wv = *(const half8*)(wp + o * HID);   // cache-resident (sorted)
            float a = 0.0f;
            #pragma unroll
            for (int pp = 0; pp < 4; ++pp) {
                half2v av = {hv[2 * pp], hv[2 * pp + 1]};
                half2v bv = {wv[2 * pp], wv[2 * pp + 1]};
                a = dot2acc(av, bv, a);
            }
            p[o] = a;
        }
        float t0 = p[0] + __shfl_xor(p[0], 1);
        float t1 = p[1] + __shfl_xor(p[1], 1);
        float t2 = p[2] + __shfl_xor(p[2], 1);
        float t3 = p[3] + __shfl_xor(p[3], 1);
        float t4 = p[4] + __shfl_xor(p[4], 1);
        float t5 = p[5] + __shfl_xor(p[5], 1);
        float t6 = p[6] + __shfl_xor(p[6], 1);
        float t7 = p[7] + __shfl_xor(p[7], 1);
        const bool b0s = (jo & 1) != 0;
        float s0 = b0s ? t1 : t0;
        float s1 = b0s ? t3 : t2;
        float s2 = b0s ? t5 : t4;
        float s3 = b0s ? t7 : t6;
        s0 += __shfl_xor(s0, 2);
        s1 += __shfl_xor(s1, 2);
        s2 += __shfl_xor(s2, 2);
        s3 += __shfl_xor(s3, 2);
        const bool b1s = (jo & 2) != 0;
        float u0 = b1s ? s1 : s0;
        float u1 = b1s ? s3 : s2;
        u0 += __shfl_xor(u0, 4);
        u1 += __shfl_xor(u1, 4);
        out[(size_t)rdx[it] * OUTF + jo] = ((jo & 4) ? u1 : u0) + hb;
    }
}

// ---------------- fused fallback (r8 verbatim) ----------------
__global__ __launch_bounds__(NTHR, 8) void fused_kernel(
    const float* __restrict__ x, const int* __restrict__ task,
    const float* __restrict__ b0, const float* __restrict__ b1,
    const float* __restrict__ b2, const float* __restrict__ hB,
    const _Float16* __restrict__ ws, float* __restrict__ out)
{
    __shared__ __align__(16) _Float16 xh[ROWS * XP];
    const int t = threadIdx.x;
    const int w = t >> 6;
    const int l = t & 63;
    const int c = l & 15;
    const int g = l >> 4;
    const int blockRow = blockIdx.x * ROWS;
    const int waveRow  = w * 32;
    const _Float16* w0f = ws + W0F_OFF / 2;
    const _Float16* w1f = ws + W1F_OFF / 2;
    const _Float16* w2f = ws + W2F_OFF / 2;
    const _Float16* hwt = ws + HWT_OFF / 2;
    const int jr = l >> 3, jo = l & 7;
    int   tks[4];
    float hBv[4];
    #pragma unroll
    for (int it = 0; it < 4; ++it) tks[it] = task[blockRow + waveRow + it * 8 + jr];
    #pragma unroll
    for (int it = 0; it < 4; ++it) hBv[it] = hB[tks[it] * OUTF + jo];
    {
        const float4* xb = reinterpret_cast<const float4*>(x + (size_t)blockRow * INF);
        #pragma unroll
        for (int i = 0; i < 12; ++i) {
            if (i < 11 || t < XTILE_V4 - 11 * NTHR) {
                float4 v = xb[t + i * NTHR];
                int e = 4 * (t + i * NTHR);
                #pragma unroll
                for (int q = 0; q < 4; ++q) {
                    int ee = e + q;
                    int rr = ee / INF, k = ee - rr * INF;
                    xh[rr * XP + k] = (_Float16)((q == 0) ? v.x : (q == 1) ? v.y
                                                 : (q == 2) ? v.z : v.w);
                }
            }
        }
        if (t < ROWS) {
            #pragma unroll
            for (int k = INF; k < 96; ++k) xh[t * XP + k] = (_Float16)0;
        }
    }
    __syncthreads();
    f32x4 acc[4][2];
    #pragma unroll
    for (int ft = 0; ft < 4; ++ft) {
        f32x4 bv = *(const f32x4*)(b0 + ft * 16 + g * 4);
        acc[ft][0] = bv; acc[ft][1] = bv;
    }
    #pragma unroll
    for (int kk = 0; kk < 3; ++kk) {
        half8 bf[2];
        #pragma unroll
        for (int bt = 0; bt < 2; ++bt)
            bf[bt] = *(const half8*)&xh[(waveRow + bt * 16 + c) * XP + kk * 32 + g * 8];
        #pragma unroll
        for (int ft = 0; ft < 4; ++ft) {
            half8 af = *(const half8*)(w0f + ((kk * 4 + ft) * 64 + l) * 8);
            acc[ft][0] = __builtin_amdgcn_mfma_f32_16x16x32_f16(af, bf[0], acc[ft][0], 0, 0, 0);
            acc[ft][1] = __builtin_amdgcn_mfma_f32_16x16x32_f16(af, bf[1], acc[ft][1], 0, 0, 0);
        }
    }
    #pragma unroll
    for (int ft = 0; ft < 4; ++ft)
        #pragma unroll
        for (int bt = 0; bt < 2; ++bt) {
            half4 hv;
            #pragma unroll
            for (int r = 0; r < 4; ++r) hv[r] = (_Float16)fast_tanh(acc[ft][bt][r]);
            *(half4*)&xh[(waveRow + bt * 16 + c) * XP + ft * 16 + g * 4] = hv;
        }
    #pragma unroll
    for (int layer = 0; layer < 2; ++layer) {
        const _Float16* WF  = layer ? w2f : w1f;
        const float*    bia = layer ? b2  : b1;
        #pragma unroll
        for (int ft = 0; ft < 4; ++ft) {
            f32x4 bv = *(const f32x4*)(bia + ft * 16 + g * 4);
            acc[ft][0] = bv; acc[ft][1] = bv;
        }
        #pragma unroll
        for (int kk = 0; kk < 2; ++kk) {
            half8 bf[2];
            #pragma unroll
            for (int bt = 0; bt < 2; ++bt)
                bf[bt] = *(const half8*)&xh[(waveRow + bt * 16 + c) * XP + kk * 32 + g * 8];
            #pragma unroll
            for (int ft = 0; ft < 4; ++ft) {
                half8 af = *(const half8*)(WF + ((kk * 4 + ft) * 64 + l) * 8);
                acc[ft][0] = __builtin_amdgcn_mfma_f32_16x16x32_f16(af, bf[0], acc[ft][0], 0, 0, 0);
                acc[ft][1] = __builtin_amdgcn_mfma_f32_16x16x32_f16(af, bf[1], acc[ft][1], 0, 0, 0);
            }
        }
        #pragma unroll
        for (int ft = 0; ft < 4; ++ft)
            #pragma unroll
            for (int bt = 0; bt < 2; ++bt) {
                half4 hv;
                #pragma unroll
                for (int r = 0; r < 4; ++r) hv[r] = (_Float16)fast_tanh(acc[ft][bt][r]);
                *(half4*)&xh[(waveRow + bt * 16 + c) * XP + ft * 16 + g * 4] = hv;
            }
    }
    #pragma unroll
    for (int it = 0; it < 4; ++it) {
        const int r = it * 8 + jr;
        const size_t grow = (size_t)blockRow + waveRow + r;
        const int tk = tks[it];
        const _Float16* wp = hwt + (size_t)tk * (OUTF * HID) + jo * 8;
        const half8 hv = *(const half8*)&xh[(waveRow + r) * XP + jo * 8];
        float p[8];
        #pragma unroll
        for (int o = 0; o < 8; ++o) {
            half8 wv = *(const half8*)(wp + o * HID);
            float a = 0.0f;
            #pragma unroll
            for (int pp = 0; pp < 4; ++pp) {
                half2v av = {hv[2 * pp], hv[2 * pp + 1]};
                half2v bv = {wv[2 * pp], wv[2 * pp + 1]};
                a = dot2acc(av, bv, a);
            }
            p[o] = a;
        }
        float t0 = p[0] + __shfl_xor(p[0], 1);
        float t1 = p[1] + __shfl_xor(p[1], 1);
        float t2 = p[2] + __shfl_xor(p[2], 1);
        float t3 = p[3] + __shfl_xor(p[3], 1);
        float t4 = p[4] + __shfl_xor(p[4], 1);
        float t5 = p[5] + __shfl_xor(p[5], 1);
        float t6 = p[6] + __shfl_xor(p[6], 1);
        float t7 = p[7] + __shfl_xor(p[7], 1);
        const bool b0s = (jo & 1) != 0;
        float s0 = b0s ? t1 : t0;
        float s1 = b0s ? t3 : t2;
        float s2 = b0s ? t5 : t4;
        float s3 = b0s ? t7 : t6;
        s0 += __shfl_xor(s0, 2);
        s1 += __shfl_xor(s1, 2);
        s2 += __shfl_xor(s2, 2);
        s3 += __shfl_xor(s3, 2);
        const bool b1s = (jo & 2) != 0;
        float u0 = b1s ? s1 : s0;
        float u1 = b1s ? s3 : s2;
        u0 += __shfl_xor(u0, 4);
        u1 += __shfl_xor(u1, 4);
        out[grow * OUTF + jo] = ((jo & 4) ? u1 : u0) + hBv[it];
    }
}

extern "C" void kernel_launch(void* const* d_in, const int* in_sizes, int n_in,
                              void* d_out, int out_size, void* d_ws, size_t ws_size,
                              hipStream_t stream) {
    const float* x    = (const float*)d_in[0];
    const int*   task = (const int*)  d_in[1];
    const float* W0   = (const float*)d_in[2];
    const float* b0   = (const float*)d_in[3];
    const float* W1   = (const float*)d_in[4];
    const float* b1   = (const float*)d_in[5];
    const float* W2   = (const float*)d_in[6];
    const float* b2   = (const float*)d_in[7];
    const float* hW   = (const float*)d_in[8];
    const float* hB   = (const float*)d_in[9];
    float* out = (float*)d_out;
    _Float16* ws = (_Float16*)d_ws;

    prep_kernel<<<64, 256, 0, stream>>>(W0, W1, W2, hW, ws);

    if (ws_size < WS_NEED) {   // workspace too small: r8 fused path
        fused_kernel<<<BN / ROWS, NTHR, 0, stream>>>(x, task, b0, b1, b2, hB, ws, out);
        return;
    }

    char* wsb = (char*)d_ws;
    int*  hist = (int*)(wsb + HIST_OFF);
    int*  base = (int*)(wsb + BASE_OFF);
    int*  idx  = (int*)(wsb + IDX_OFF);
    _Float16* hbuf = (_Float16*)(wsb + H_OFF);

    sort_init   <<<1,   128, 0, stream>>>(hist, base);
    sort_hist   <<<256, 256, 0, stream>>>(task, hist);
    sort_prefix <<<1,    64, 0, stream>>>(hist, base);
    sort_scatter<<<256, 256, 0, stream>>>(task, base, idx);
    trunk_kernel<<<BN / ROWS, NTHR, 0, stream>>>(x, b0, b1, b2, ws, hbuf);
    head_kernel <<<BN / 128, 256, 0, stream>>>(idx, task, ws, hB, out);
}

// Round 11
// 59.103 us; speedup vs baseline: 1.2851x; 1.2851x over previous
//
#include <hip/hip_runtime.h>
#include <stdint.h>
#include <stddef.h>

// MultiTaskTrunkNetwork: 3x (Linear+Tanh) [89->64->64->64] + per-task head [64->8]
// Round 11: 2-tile ILP per wave (r10 falsified the split: trunk IS the cost, all
// pipes idle -> latency-chain-bound; occupancy pinned at ~12 waves/CU).
//   - 128-thr / 2-wave blocks, 128 rows/block: each wave owns 64 rows as TWO
//     independent 32-row tiles -> 2x independent MFMA/LDS chains per wave,
//     A-fragment loads amortized over 4 MFMAs (was 2)
//   - staging, frag-ordered weights, pitch-104 LDS, r6 head: unchanged

typedef _Float16 half8 __attribute__((ext_vector_type(8)));
typedef _Float16 half4 __attribute__((ext_vector_type(4)));
typedef _Float16 half2v __attribute__((ext_vector_type(2)));
typedef float    f32x4 __attribute__((ext_vector_type(4)));

constexpr int BN = 262144, INF = 89, HID = 64, OUTF = 8, NTASK = 50;
constexpr int NTHR = 128;     // 2 waves
constexpr int ROWS = 128;     // batch rows per block (64 per wave, 2 tiles of 32)
constexpr int XP   = 104;     // LDS row pitch in f16 (208 B)
constexpr int XTILE_V4 = ROWS * INF / 4;   // 2848 float4 = 22*128 + 32

// d_ws layout (bytes) — fragment-ordered weights
constexpr int W0F_OFF = 0;        // [3kk][4ft][64lane][8] f16 = 12288 B (k>=89 zero)
constexpr int W1F_OFF = 12288;    // [2kk][4ft][64lane][8] f16 = 8192 B
constexpr int W2F_OFF = 20480;    // [2kk][4ft][64lane][8] f16 = 8192 B
constexpr int HWT_OFF = 28672;    // [50][8][64] f16 (transposed head weights)

__device__ __forceinline__ float fast_tanh(float v) {
    float e = __expf(2.0f * v);
    return 1.0f - 2.0f * __builtin_amdgcn_rcpf(e + 1.0f);
}

__device__ __forceinline__ float dot2acc(half2v a, half2v b, float c) {
#if __has_builtin(__builtin_amdgcn_fdot2)
    return __builtin_amdgcn_fdot2(a, b, c, false);
#else
    return fmaf((float)a[0], (float)b[0], fmaf((float)a[1], (float)b[1], c));
#endif
}

__global__ void prep_kernel(const float* __restrict__ W0, const float* __restrict__ W1,
                            const float* __restrict__ W2, const float* __restrict__ hW,
                            _Float16* __restrict__ ws) {
    const int tid = blockIdx.x * blockDim.x + threadIdx.x;
    const int stride = gridDim.x * blockDim.x;
    _Float16* w0f = ws + W0F_OFF / 2;
    _Float16* w1f = ws + W1F_OFF / 2;
    _Float16* w2f = ws + W2F_OFF / 2;
    _Float16* hwt = ws + HWT_OFF / 2;
    for (int i = tid; i < 3 * 4 * 64 * 8; i += stride) {
        int j = i & 7, l = (i >> 3) & 63, fk = i >> 9;   // fk = kk*4+ft
        int kk = fk >> 2, ft = fk & 3;
        int n = ft * 16 + (l & 15);
        int k = kk * 32 + (l >> 4) * 8 + j;
        w0f[i] = (_Float16)(k < INF ? W0[k * HID + n] : 0.0f);
    }
    for (int i = tid; i < 2 * 4 * 64 * 8; i += stride) {
        int j = i & 7, l = (i >> 3) & 63, fk = i >> 9;
        int kk = fk >> 2, ft = fk & 3;
        int n = ft * 16 + (l & 15);
        int k = kk * 32 + (l >> 4) * 8 + j;
        w1f[i] = (_Float16)W1[k * HID + n];
        w2f[i] = (_Float16)W2[k * HID + n];
    }
    for (int i = tid; i < NTASK * OUTF * HID; i += stride) {   // hwT[t][o][k]
        int t = i / (OUTF * HID), rem = i % (OUTF * HID);
        int o = rem / HID, k = rem % HID;
        hwt[i] = (_Float16)hW[(size_t)t * (HID * OUTF) + k * OUTF + o];
    }
}

__global__ __launch_bounds__(NTHR, 3) void mtn_mfma_kernel(
    const float* __restrict__ x,     // [B, 89]
    const int*   __restrict__ task,  // [B]
    const float* __restrict__ b0, const float* __restrict__ b1,
    const float* __restrict__ b2,
    const float* __restrict__ hB,    // [50, 8] fp32
    const _Float16* __restrict__ ws,
    float* __restrict__ out)         // [B, 8]
{
    __shared__ __align__(16) _Float16 xh[ROWS * XP];   // 26624 B; x tile, then h

    const int t = threadIdx.x;
    const int w = t >> 6;            // wave 0..1
    const int l = t & 63;
    const int c = l & 15;            // MFMA col (batch) / A row (feat)
    const int g = l >> 4;            // k-group / D row-group
    const int blockRow = blockIdx.x * ROWS;
    const int waveRow  = w * 64;     // this wave's private 64-row LDS band

    const _Float16* w0f = ws + W0F_OFF / 2;
    const _Float16* w1f = ws + W1F_OFF / 2;
    const _Float16* w2f = ws + W2F_OFF / 2;
    const _Float16* hwt = ws + HWT_OFF / 2;

    // ---- prefetch task indices + head biases (issued ~whole kernel early)
    const int jr = l >> 3, jo = l & 7;
    int   tks[8];
    float hBv[8];
    #pragma unroll
    for (int it = 0; it < 8; ++it)
        tks[it] = task[blockRow + waveRow + it * 8 + jr];
    #pragma unroll
    for (int it = 0; it < 8; ++it)
        hBv[it] = hB[tks[it] * OUTF + jo];

    // ---- stage x tile: coalesced float4 flat loads -> f16 LDS [row][k], pitch 104
    {
        const float4* xb = reinterpret_cast<const float4*>(x + (size_t)blockRow * INF);
        #pragma unroll
        for (int i = 0; i < 23; ++i) {
            if (i < 22 || t < XTILE_V4 - 22 * NTHR) {        // 2848 = 22*128 + 32
                float4 v = xb[t + i * NTHR];
                int e = 4 * (t + i * NTHR);
                #pragma unroll
                for (int q = 0; q < 4; ++q) {
                    int ee = e + q;
                    int rr = ee / INF, k = ee - rr * INF;
                    xh[rr * XP + k] = (_Float16)((q == 0) ? v.x : (q == 1) ? v.y
                                                 : (q == 2) ? v.z : v.w);
                }
            }
        }
        // zero-pad k = 89..95 for all 128 rows (one row per thread)
        #pragma unroll
        for (int k = INF; k < 96; ++k) xh[t * XP + k] = (_Float16)0;
    }
    __syncthreads();   // only barrier: after this, each wave touches only its band

    f32x4 acc[4][4];   // [feat-tile][tile*2 + batch-sub]: 2 independent 32-row tiles

    // ================= layer 0: K=96 (89 padded), B from LDS, A frag-ordered =========
    #pragma unroll
    for (int ft = 0; ft < 4; ++ft) {
        f32x4 bv = *(const f32x4*)(b0 + ft * 16 + g * 4);
        acc[ft][0] = bv; acc[ft][1] = bv; acc[ft][2] = bv; acc[ft][3] = bv;
    }
    #pragma unroll
    for (int kk = 0; kk < 3; ++kk) {
        half8 bf[4];
        #pragma unroll
        for (int q = 0; q < 4; ++q) {            // q = tt*2 + bt: row tt*32 + bt*16
            const int row = waveRow + (q >> 1) * 32 + (q & 1) * 16 + c;
            bf[q] = *(const half8*)&xh[row * XP + kk * 32 + g * 8];
        }
        #pragma unroll
        for (int ft = 0; ft < 4; ++ft) {
            half8 af = *(const half8*)(w0f + ((kk * 4 + ft) * 64 + l) * 8);  // 16B/lane
            #pragma unroll
            for (int q = 0; q < 4; ++q)
                acc[ft][q] = __builtin_amdgcn_mfma_f32_16x16x32_f16(af, bf[q], acc[ft][q], 0, 0, 0);
        }
    }
    #pragma unroll
    for (int ft = 0; ft < 4; ++ft)
        #pragma unroll
        for (int q = 0; q < 4; ++q) {
            half4 hv;
            #pragma unroll
            for (int r = 0; r < 4; ++r) hv[r] = (_Float16)fast_tanh(acc[ft][q][r]);
            const int row = waveRow + (q >> 1) * 32 + (q & 1) * 16 + c;
            *(half4*)&xh[row * XP + ft * 16 + g * 4] = hv;   // 8B store
        }

    // ================= layers 1,2: K=64 =================
    #pragma unroll
    for (int layer = 0; layer < 2; ++layer) {
        const _Float16* WF  = layer ? w2f : w1f;
        const float*    bia = layer ? b2  : b1;
        #pragma unroll
        for (int ft = 0; ft < 4; ++ft) {
            f32x4 bv = *(const f32x4*)(bia + ft * 16 + g * 4);
            acc[ft][0] = bv; acc[ft][1] = bv; acc[ft][2] = bv; acc[ft][3] = bv;
        }
        #pragma unroll
        for (int kk = 0; kk < 2; ++kk) {
            half8 bf[4];
            #pragma unroll
            for (int q = 0; q < 4; ++q) {
                const int row = waveRow + (q >> 1) * 32 + (q & 1) * 16 + c;
                bf[q] = *(const half8*)&xh[row * XP + kk * 32 + g * 8];
            }
            #pragma unroll
            for (int ft = 0; ft < 4; ++ft) {
                half8 af = *(const half8*)(WF + ((kk * 4 + ft) * 64 + l) * 8);
                #pragma unroll
                for (int q = 0; q < 4; ++q)
                    acc[ft][q] = __builtin_amdgcn_mfma_f32_16x16x32_f16(af, bf[q], acc[ft][q], 0, 0, 0);
            }
        }
        #pragma unroll
        for (int ft = 0; ft < 4; ++ft)
            #pragma unroll
            for (int q = 0; q < 4; ++q) {
                half4 hv;
                #pragma unroll
                for (int r = 0; r < 4; ++r) hv[r] = (_Float16)fast_tanh(acc[ft][q][r]);
                const int row = waveRow + (q >> 1) * 32 + (q & 1) * 16 + c;
                *(half4*)&xh[row * XP + ft * 16 + g * 4] = hv;
            }
    }

    // ================= head: coalesced weight chunks + transpose-reduce =============
    #pragma unroll
    for (int it = 0; it < 8; ++it) {
        const int r = it * 8 + jr;                       // 0..63 within wave band
        const size_t grow = (size_t)blockRow + waveRow + r;
        const int tk = tks[it];
        const _Float16* wp = hwt + (size_t)tk * (OUTF * HID) + jo * 8;  // chunk jo
        const half8 hv = *(const half8*)&xh[(waveRow + r) * XP + jo * 8]; // 1 read/it

        float p[8];
        #pragma unroll
        for (int o = 0; o < 8; ++o) {
            half8 wv = *(const half8*)(wp + o * HID);   // 8 lanes -> 128B contiguous
            float a = 0.0f;
            #pragma unroll
            for (int pp = 0; pp < 4; ++pp) {
                half2v av = {hv[2 * pp], hv[2 * pp + 1]};
                half2v bv = {wv[2 * pp], wv[2 * pp + 1]};
                a = dot2acc(av, bv, a);
            }
            p[o] = a;
        }
        // transpose-reduce across the 8 jo-lanes (static indices only)
        float t0 = p[0] + __shfl_xor(p[0], 1);
        float t1 = p[1] + __shfl_xor(p[1], 1);
        float t2 = p[2] + __shfl_xor(p[2], 1);
        float t3 = p[3] + __shfl_xor(p[3], 1);
        float t4 = p[4] + __shfl_xor(p[4], 1);
        float t5 = p[5] + __shfl_xor(p[5], 1);
        float t6 = p[6] + __shfl_xor(p[6], 1);
        float t7 = p[7] + __shfl_xor(p[7], 1);
        const bool b0s = (jo & 1) != 0;
        float s0 = b0s ? t1 : t0;
        float s1 = b0s ? t3 : t2;
        float s2 = b0s ? t5 : t4;
        float s3 = b0s ? t7 : t6;
        s0 += __shfl_xor(s0, 2);
        s1 += __shfl_xor(s1, 2);
        s2 += __shfl_xor(s2, 2);
        s3 += __shfl_xor(s3, 2);
        const bool b1s = (jo & 2) != 0;
        float u0 = b1s ? s1 : s0;
        float u1 = b1s ? s3 : s2;
        u0 += __shfl_xor(u0, 4);
        u1 += __shfl_xor(u1, 4);
        float res = ((jo & 4) ? u1 : u0) + hBv[it];
        out[grow * OUTF + jo] = res;    // wave stores 64 consecutive dwords
    }
}

extern "C" void kernel_launch(void* const* d_in, const int* in_sizes, int n_in,
                              void* d_out, int out_size, void* d_ws, size_t ws_size,
                              hipStream_t stream) {
    const float* x    = (const float*)d_in[0];
    const int*   task = (const int*)  d_in[1];
    const float* W0   = (const float*)d_in[2];
    const float* b0   = (const float*)d_in[3];
    const float* W1   = (const float*)d_in[4];
    const float* b1   = (const float*)d_in[5];
    const float* W2   = (const float*)d_in[6];
    const float* b2   = (const float*)d_in[7];
    const float* hW   = (const float*)d_in[8];
    const float* hB   = (const float*)d_in[9];
    float* out = (float*)d_out;
    _Float16* ws = (_Float16*)d_ws;

    prep_kernel<<<64, 256, 0, stream>>>(W0, W1, W2, hW, ws);
    mtn_mfma_kernel<<<BN / ROWS, NTHR, 0, stream>>>(x, task, b0, b1, b2, hB, ws, out);
}

// Round 12
// 45.099 us; speedup vs baseline: 1.6841x; 1.3105x over previous
//
#include <hip/hip_runtime.h>
#include <stdint.h>
#include <stddef.h>

// MultiTaskTrunkNetwork: 3x (Linear+Tanh) [89->64->64->64] + per-task head [64->8]
// Round 12: r8 exactly, except the staging-load serialization fix.
//   THEORY: r8's __launch_bounds__(128,8) -> 64-VGPR budget forced the compiler
//   to serialize the 12 staging loads (load->wait->use x12 ~= 7200 cyc/wave).
//   Fix: bounds (128,4) (budget 128) + explicit float4 v[12] hoist so all loads
//   are in flight simultaneously. Everything else identical to r8 (43.9 us).

typedef _Float16 half8 __attribute__((ext_vector_type(8)));
typedef _Float16 half4 __attribute__((ext_vector_type(4)));
typedef _Float16 half2v __attribute__((ext_vector_type(2)));
typedef float    f32x4 __attribute__((ext_vector_type(4)));

constexpr int BN = 262144, INF = 89, HID = 64, OUTF = 8, NTASK = 50;
constexpr int NTHR = 128;     // 2 waves
constexpr int ROWS = 64;      // batch rows per block (32 per wave)
constexpr int XP   = 104;     // LDS row pitch in f16 (208 B)
constexpr int XTILE_V4 = ROWS * INF / 4;   // 1424 float4 = 11*128 + 16

// d_ws layout (bytes) — fragment-ordered weights
constexpr int W0F_OFF = 0;        // [3kk][4ft][64lane][8] f16 = 12288 B (k>=89 zero)
constexpr int W1F_OFF = 12288;    // [2kk][4ft][64lane][8] f16 = 8192 B
constexpr int W2F_OFF = 20480;    // [2kk][4ft][64lane][8] f16 = 8192 B
constexpr int HWT_OFF = 28672;    // [50][8][64] f16 (transposed head weights)

__device__ __forceinline__ float fast_tanh(float v) {
    float e = __expf(2.0f * v);
    return 1.0f - 2.0f * __builtin_amdgcn_rcpf(e + 1.0f);
}

__device__ __forceinline__ float dot2acc(half2v a, half2v b, float c) {
#if __has_builtin(__builtin_amdgcn_fdot2)
    return __builtin_amdgcn_fdot2(a, b, c, false);
#else
    return fmaf((float)a[0], (float)b[0], fmaf((float)a[1], (float)b[1], c));
#endif
}

__global__ void prep_kernel(const float* __restrict__ W0, const float* __restrict__ W1,
                            const float* __restrict__ W2, const float* __restrict__ hW,
                            _Float16* __restrict__ ws) {
    const int tid = blockIdx.x * blockDim.x + threadIdx.x;
    const int stride = gridDim.x * blockDim.x;
    _Float16* w0f = ws + W0F_OFF / 2;
    _Float16* w1f = ws + W1F_OFF / 2;
    _Float16* w2f = ws + W2F_OFF / 2;
    _Float16* hwt = ws + HWT_OFF / 2;
    for (int i = tid; i < 3 * 4 * 64 * 8; i += stride) {
        int j = i & 7, l = (i >> 3) & 63, fk = i >> 9;   // fk = kk*4+ft
        int kk = fk >> 2, ft = fk & 3;
        int n = ft * 16 + (l & 15);
        int k = kk * 32 + (l >> 4) * 8 + j;
        w0f[i] = (_Float16)(k < INF ? W0[k * HID + n] : 0.0f);
    }
    for (int i = tid; i < 2 * 4 * 64 * 8; i += stride) {
        int j = i & 7, l = (i >> 3) & 63, fk = i >> 9;
        int kk = fk >> 2, ft = fk & 3;
        int n = ft * 16 + (l & 15);
        int k = kk * 32 + (l >> 4) * 8 + j;
        w1f[i] = (_Float16)W1[k * HID + n];
        w2f[i] = (_Float16)W2[k * HID + n];
    }
    for (int i = tid; i < NTASK * OUTF * HID; i += stride) {   // hwT[t][o][k]
        int t = i / (OUTF * HID), rem = i % (OUTF * HID);
        int o = rem / HID, k = rem % HID;
        hwt[i] = (_Float16)hW[(size_t)t * (HID * OUTF) + k * OUTF + o];
    }
}

__global__ __launch_bounds__(NTHR, 4) void mtn_mfma_kernel(
    const float* __restrict__ x,     // [B, 89]
    const int*   __restrict__ task,  // [B]
    const float* __restrict__ b0, const float* __restrict__ b1,
    const float* __restrict__ b2,
    const float* __restrict__ hB,    // [50, 8] fp32
    const _Float16* __restrict__ ws,
    float* __restrict__ out)         // [B, 8]
{
    __shared__ __align__(16) _Float16 xh[ROWS * XP];   // 13312 B; x tile, then h in-place

    const int t = threadIdx.x;
    const int w = t >> 6;            // wave 0..1
    const int l = t & 63;
    const int c = l & 15;            // MFMA col (batch) / A row (feat)
    const int g = l >> 4;            // k-group / D row-group
    const int blockRow = blockIdx.x * ROWS;
    const int waveRow  = w * 32;     // this wave's private 32-row LDS band

    const _Float16* w0f = ws + W0F_OFF / 2;
    const _Float16* w1f = ws + W1F_OFF / 2;
    const _Float16* w2f = ws + W2F_OFF / 2;
    const _Float16* hwt = ws + HWT_OFF / 2;

    // ---- prefetch task indices + head biases (issued ~whole kernel early)
    const int jr = l >> 3, jo = l & 7;
    int   tks[4];
    float hBv[4];
    #pragma unroll
    for (int it = 0; it < 4; ++it)
        tks[it] = task[blockRow + waveRow + it * 8 + jr];
    #pragma unroll
    for (int it = 0; it < 4; ++it)
        hBv[it] = hB[tks[it] * OUTF + jo];

    // ---- stage x tile: ALL loads issued first (explicit register hoist), then
    //      convert+write. 1424 float4 = 11*128 + 16-thread tail.
    {
        const float4* xb = reinterpret_cast<const float4*>(x + (size_t)blockRow * INF);
        const bool tail = t < (XTILE_V4 - 11 * NTHR);   // t < 16
        float4 v[12];
        #pragma unroll
        for (int i = 0; i < 11; ++i) v[i] = xb[t + i * NTHR];   // 11 loads in flight
        if (tail) v[11] = xb[t + 11 * NTHR];
        #pragma unroll
        for (int i = 0; i < 12; ++i) {
            if (i < 11 || tail) {
                int e = 4 * (t + i * NTHR);
                #pragma unroll
                for (int q = 0; q < 4; ++q) {
                    int ee = e + q;
                    int rr = ee / INF, k = ee - rr * INF;
                    xh[rr * XP + k] = (_Float16)((q == 0) ? v[i].x : (q == 1) ? v[i].y
                                                 : (q == 2) ? v[i].z : v[i].w);
                }
            }
        }
        if (t < ROWS) {                 // zero-pad k = 89..95
            #pragma unroll
            for (int k = INF; k < 96; ++k) xh[t * XP + k] = (_Float16)0;
        }
    }
    __syncthreads();   // only barrier: after this, each wave owns its band

    f32x4 acc[4][2];   // [feat-tile][batch-tile]

    // ================= layer 0: K=96 (89 padded), B from LDS, A frag-ordered =========
    #pragma unroll
    for (int ft = 0; ft < 4; ++ft) {
        f32x4 bv = *(const f32x4*)(b0 + ft * 16 + g * 4);
        acc[ft][0] = bv; acc[ft][1] = bv;
    }
    #pragma unroll
    for (int kk = 0; kk < 3; ++kk) {
        half8 bf[2];
        #pragma unroll
        for (int bt = 0; bt < 2; ++bt)
            bf[bt] = *(const half8*)&xh[(waveRow + bt * 16 + c) * XP + kk * 32 + g * 8];
        #pragma unroll
        for (int ft = 0; ft < 4; ++ft) {
            half8 af = *(const half8*)(w0f + ((kk * 4 + ft) * 64 + l) * 8);  // 16B/lane
            acc[ft][0] = __builtin_amdgcn_mfma_f32_16x16x32_f16(af, bf[0], acc[ft][0], 0, 0, 0);
            acc[ft][1] = __builtin_amdgcn_mfma_f32_16x16x32_f16(af, bf[1], acc[ft][1], 0, 0, 0);
        }
    }
    #pragma unroll
    for (int ft = 0; ft < 4; ++ft)
        #pragma unroll
        for (int bt = 0; bt < 2; ++bt) {
            half4 hv;
            #pragma unroll
            for (int r = 0; r < 4; ++r) hv[r] = (_Float16)fast_tanh(acc[ft][bt][r]);
            *(half4*)&xh[(waveRow + bt * 16 + c) * XP + ft * 16 + g * 4] = hv;
        }

    // ================= layers 1,2: K=64 =================
    #pragma unroll
    for (int layer = 0; layer < 2; ++layer) {
        const _Float16* WF  = layer ? w2f : w1f;
        const float*    bia = layer ? b2  : b1;
        #pragma unroll
        for (int ft = 0; ft < 4; ++ft) {
            f32x4 bv = *(const f32x4*)(bia + ft * 16 + g * 4);
            acc[ft][0] = bv; acc[ft][1] = bv;
        }
        #pragma unroll
        for (int kk = 0; kk < 2; ++kk) {
            half8 bf[2];
            #pragma unroll
            for (int bt = 0; bt < 2; ++bt)
                bf[bt] = *(const half8*)&xh[(waveRow + bt * 16 + c) * XP + kk * 32 + g * 8];
            #pragma unroll
            for (int ft = 0; ft < 4; ++ft) {
                half8 af = *(const half8*)(WF + ((kk * 4 + ft) * 64 + l) * 8);
                acc[ft][0] = __builtin_amdgcn_mfma_f32_16x16x32_f16(af, bf[0], acc[ft][0], 0, 0, 0);
                acc[ft][1] = __builtin_amdgcn_mfma_f32_16x16x32_f16(af, bf[1], acc[ft][1], 0, 0, 0);
            }
        }
        #pragma unroll
        for (int ft = 0; ft < 4; ++ft)
            #pragma unroll
            for (int bt = 0; bt < 2; ++bt) {
                half4 hv;
                #pragma unroll
                for (int r = 0; r < 4; ++r) hv[r] = (_Float16)fast_tanh(acc[ft][bt][r]);
                *(half4*)&xh[(waveRow + bt * 16 + c) * XP + ft * 16 + g * 4] = hv;
            }
    }

    // ================= head: coalesced weight chunks + transpose-reduce =============
    #pragma unroll
    for (int it = 0; it < 4; ++it) {
        const int r = it * 8 + jr;
        const size_t grow = (size_t)blockRow + waveRow + r;
        const int tk = tks[it];
        const _Float16* wp = hwt + (size_t)tk * (OUTF * HID) + jo * 8;  // chunk jo
        const half8 hv = *(const half8*)&xh[(waveRow + r) * XP + jo * 8]; // 1 read/it

        float p[8];
        #pragma unroll
        for (int o = 0; o < 8; ++o) {
            half8 wv = *(const half8*)(wp + o * HID);   // 8 lanes -> 128B contiguous
            float a = 0.0f;
            #pragma unroll
            for (int pp = 0; pp < 4; ++pp) {
                half2v av = {hv[2 * pp], hv[2 * pp + 1]};
                half2v bv = {wv[2 * pp], wv[2 * pp + 1]};
                a = dot2acc(av, bv, a);
            }
            p[o] = a;
        }
        // transpose-reduce across the 8 jo-lanes (static indices only)
        float t0 = p[0] + __shfl_xor(p[0], 1);
        float t1 = p[1] + __shfl_xor(p[1], 1);
        float t2 = p[2] + __shfl_xor(p[2], 1);
        float t3 = p[3] + __shfl_xor(p[3], 1);
        float t4 = p[4] + __shfl_xor(p[4], 1);
        float t5 = p[5] + __shfl_xor(p[5], 1);
        float t6 = p[6] + __shfl_xor(p[6], 1);
        float t7 = p[7] + __shfl_xor(p[7], 1);
        const bool b0s = (jo & 1) != 0;
        float s0 = b0s ? t1 : t0;
        float s1 = b0s ? t3 : t2;
        float s2 = b0s ? t5 : t4;
        float s3 = b0s ? t7 : t6;
        s0 += __shfl_xor(s0, 2);
        s1 += __shfl_xor(s1, 2);
        s2 += __shfl_xor(s2, 2);
        s3 += __shfl_xor(s3, 2);
        const bool b1s = (jo & 2) != 0;
        float u0 = b1s ? s1 : s0;
        float u1 = b1s ? s3 : s2;
        u0 += __shfl_xor(u0, 4);
        u1 += __shfl_xor(u1, 4);
        float res = ((jo & 4) ? u1 : u0) + hBv[it];
        out[grow * OUTF + jo] = res;    // wave stores 64 consecutive dwords
    }
}

extern "C" void kernel_launch(void* const* d_in, const int* in_sizes, int n_in,
                              void* d_out, int out_size, void* d_ws, size_t ws_size,
                              hipStream_t stream) {
    const float* x    = (const float*)d_in[0];
    const int*   task = (const int*)  d_in[1];
    const float* W0   = (const float*)d_in[2];
    const float* b0   = (const float*)d_in[3];
    const float* W1   = (const float*)d_in[4];
    const float* b1   = (const float*)d_in[5];
    const float* W2   = (const float*)d_in[6];
    const float* b2   = (const float*)d_in[7];
    const float* hW   = (const float*)d_in[8];
    const float* hB   = (const float*)d_in[9];
    float* out = (float*)d_out;
    _Float16* ws = (_Float16*)d_ws;

    prep_kernel<<<64, 256, 0, stream>>>(W0, W1, W2, hW, ws);
    mtn_mfma_kernel<<<BN / ROWS, NTHR, 0, stream>>>(x, task, b0, b1, b2, hB, ws, out);
}